// Round 6
// baseline (170.663 us; speedup 1.0000x reference)
//
#include <hip/hip_runtime.h>
#include <hip/hip_bf16.h>

typedef __bf16 bf16_t;
typedef __bf16 bf16x8 __attribute__((ext_vector_type(8)));
typedef float f32x4 __attribute__((ext_vector_type(4)));
typedef float f32x16 __attribute__((ext_vector_type(16)));

#define NV 8000   // D*H*W
#define QB 125    // NV / 64

#define GLOAD_LDS16(src, dst) \
    __builtin_amdgcn_global_load_lds((const __attribute__((address_space(1))) void*)(src), \
                                     (__attribute__((address_space(3))) void*)(dst), 16, 0, 0)

__device__ __forceinline__ bf16x8 cvt_bf16x8(const float* __restrict__ p) {
    float4 a = *reinterpret_cast<const float4*>(p);
    float4 b = *reinterpret_cast<const float4*>(p + 4);
    bf16x8 r;
    r[0] = (bf16_t)a.x; r[1] = (bf16_t)a.y; r[2] = (bf16_t)a.z; r[3] = (bf16_t)a.w;
    r[4] = (bf16_t)b.x; r[5] = (bf16_t)b.y; r[6] = (bf16_t)b.z; r[7] = (bf16_t)b.w;
    return r;
}

__device__ __forceinline__ unsigned pack2(float a, float b) {
    union { bf16_t h[2]; unsigned u; } x;
    x.h[0] = (bf16_t)a; x.h[1] = (bf16_t)b;
    return x.u;
}

// sigma permutation: n = 125c + a  ->  sigma = 64a + c (projection gather
// becomes contiguous).
__device__ __forceinline__ int sigma_of(int n) {
    int c = n / 125, a = n - 125 * c;
    return a * 64 + c;
}

// ---------------------------------------------------------------------------
// Kernel 1: fused QKV convs, 16-voxel tiles (grid 2*500).  (unchanged, R5)
// ---------------------------------------------------------------------------
__global__ __launch_bounds__(256) void qkv_kernel(
    const float* __restrict__ x,
    const float* __restrict__ wq, const float* __restrict__ bq,
    const float* __restrict__ wk, const float* __restrict__ bk,
    const float* __restrict__ wv, const float* __restrict__ bv,
    bf16_t* __restrict__ Q, bf16_t* __restrict__ Kr, bf16_t* __restrict__ Vt)
{
    __shared__ __align__(16) char xb[16 * 128];

    const int tid = threadIdx.x;
    const int b  = blockIdx.x / 500;
    const int n0 = (blockIdx.x % 500) * 16;

    {
        int c = tid >> 2, seg = tid & 3;
        float4 v4 = *reinterpret_cast<const float4*>(&x[((size_t)b * 64 + c) * NV + n0 + seg * 4]);
        #pragma unroll
        for (int j = 0; j < 4; ++j) {
            int vx = seg * 4 + j;
            *reinterpret_cast<bf16_t*>(xb + vx * 128 + ((c * 2) ^ ((vx & 7) << 4))) =
                (bf16_t)((&v4.x)[j]);
        }
    }
    __syncthreads();

    const int w  = tid >> 6;
    const int lane = tid & 63;
    const int g  = lane >> 4;
    const int lr = lane & 15;

    const bf16x8 xa0 = *reinterpret_cast<const bf16x8*>(
        xb + lr * 128 + ((16 * g) ^ ((lr & 7) << 4)));
    const bf16x8 xa1 = *reinterpret_cast<const bf16x8*>(
        xb + lr * 128 + ((64 + 16 * g) ^ ((lr & 7) << 4)));

    const f32x4 zero4 = {0.f, 0.f, 0.f, 0.f};
    const float QSCALE = 0.125f * 1.44269504088896f;
    const int kout = w * 16 + lr;

    {   // Q (sigma-ordered)
        bf16x8 wb0 = cvt_bf16x8(wq + kout * 64 + 8 * g);
        bf16x8 wb1 = cvt_bf16x8(wq + kout * 64 + 32 + 8 * g);
        f32x4 acc = __builtin_amdgcn_mfma_f32_16x16x32_bf16(xa0, wb0, zero4, 0, 0, 0);
        acc = __builtin_amdgcn_mfma_f32_16x16x32_bf16(xa1, wb1, acc, 0, 0, 0);
        const float bias = bq[kout];
        #pragma unroll
        for (int j = 0; j < 4; ++j) {
            const int sig = sigma_of(n0 + 4 * g + j);
            Q[((size_t)b * NV + sig) * 64 + kout] = (bf16_t)((acc[j] + bias) * QSCALE);
        }
    }
    {   // K (n-ordered)
        bf16x8 wb0 = cvt_bf16x8(wk + kout * 64 + 8 * g);
        bf16x8 wb1 = cvt_bf16x8(wk + kout * 64 + 32 + 8 * g);
        f32x4 acc = __builtin_amdgcn_mfma_f32_16x16x32_bf16(xa0, wb0, zero4, 0, 0, 0);
        acc = __builtin_amdgcn_mfma_f32_16x16x32_bf16(xa1, wb1, acc, 0, 0, 0);
        const float bias = bk[kout];
        #pragma unroll
        for (int j = 0; j < 4; ++j)
            Kr[((size_t)b * NV + n0 + 4 * g + j) * 64 + kout] = (bf16_t)(acc[j] + bias);
    }
    {   // V (n-ordered, packed)
        bf16x8 wb0 = cvt_bf16x8(wv + kout * 64 + 8 * g);
        bf16x8 wb1 = cvt_bf16x8(wv + kout * 64 + 32 + 8 * g);
        f32x4 acc = __builtin_amdgcn_mfma_f32_16x16x32_bf16(xa0, wb0, zero4, 0, 0, 0);
        acc = __builtin_amdgcn_mfma_f32_16x16x32_bf16(xa1, wb1, acc, 0, 0, 0);
        const float bias = bv[kout];
        union { uint2 u2; bf16_t h[4]; } pk;
        #pragma unroll
        for (int j = 0; j < 4; ++j) pk.h[j] = (bf16_t)(acc[j] + bias);
        *reinterpret_cast<uint2*>(&Vt[((size_t)b * 64 + kout) * NV + n0 + 4 * g]) = pk.u2;
    }
}

// ---------------------------------------------------------------------------
// Kernel 2: flash attention, 32x32x16 MFMA, 4 waves x 32 queries = 128 q/blk.
// K/V double-buffered via global_load_lds with pre-swizzled SOURCE (linear
// LDS dest, XOR swizzle applied on the read side).  Swapped operands:
// S^T = mfma(A=K, B=Q) -> lane col = query; softmax needs 1 shuffle.
// O^T = mfma(A=V, B=P).  Defer-max THR=8 (exp2 domain).  Split-K S-way.
// ---------------------------------------------------------------------------
template<int S>
__global__ __launch_bounds__(256) void attn_kernel(
    const bf16_t* __restrict__ Q, const bf16_t* __restrict__ Kr,
    const bf16_t* __restrict__ Vt, float* __restrict__ Op, float* __restrict__ ml)
{
    __shared__ __align__(16) char kt[2][8192];
    __shared__ __align__(16) char vt[2][8192];
    __shared__ __align__(16) char pt[4][4096];

    const int tid  = threadIdx.x;
    const int s    = blockIdx.x % S;
    const int rem  = blockIdx.x / S;
    const int b    = rem / 63;
    const int qb   = rem % 63;
    const int q0   = qb * 128;
    const int t0   = (125 * s) / S;
    const int t1   = (125 * (s + 1)) / S;
    const int w    = tid >> 6;
    const int lane = tid & 63;
    const int lo   = lane & 31;
    const int hi   = lane >> 5;

    const int q  = q0 + w * 32 + lo;          // sigma-space query row
    const int qc = q < NV ? q : NV - 1;       // clamped for loads

    // Q fragments (B operand): bq[kk] = Q[qc][kk*16 + hi*8 .. +7]
    bf16x8 bq[4];
    {
        const bf16_t* qrow = Q + ((size_t)b * NV + qc) * 64 + hi * 8;
        #pragma unroll
        for (int kk = 0; kk < 4; ++kk)
            bq[kk] = *reinterpret_cast<const bf16x8*>(qrow + kk * 16);
    }

    const char* kp = (const char*)(Kr + (size_t)b * NV * 64);
    const char* vp = (const char*)(Vt + (size_t)b * 64 * NV);

    // staging geometry: wave w fills rows w*16..w*16+15 of each 64x128B tile
    const int srr = lane >> 3;                // 0..7
    const int sch = lane & 7;                 // 16B chunk in row

    f32x16 acco[2]; acco[0] = f32x16{}; acco[1] = f32x16{};
    float m = -1e30f, l = 0.f;

    char* ptw = &pt[w][0] + lo * 128;         // P row for query lo (64 keys bf16)
    const int swzq = (lo & 7) << 4;

    // prologue stage of tile t0 into buffer 0
    {
        const int m0 = t0 * 64;
        #pragma unroll
        for (int rnd = 0; rnd < 2; ++rnd) {
            const int r = w * 16 + rnd * 8 + srr;
            const int cb = (sch * 16) ^ ((r & 7) << 4);
            GLOAD_LDS16(kp + (size_t)(m0 + r) * 128 + cb, kt[0] + w * 2048 + rnd * 1024);
            GLOAD_LDS16(vp + (size_t)r * (NV * 2) + m0 * 2 + cb, vt[0] + w * 2048 + rnd * 1024);
        }
    }

    for (int t = t0; t < t1; ++t) {
        const int cur = (t - t0) & 1;
        __syncthreads();   // own vmcnt(0) drains own stage; barrier -> buf[cur] ready,
                           // and buf[cur^1] fully consumed (prev iter's reads done)
        if (t + 1 < t1) {
            const int m0n = (t + 1) * 64;
            #pragma unroll
            for (int rnd = 0; rnd < 2; ++rnd) {
                const int r = w * 16 + rnd * 8 + srr;
                const int cb = (sch * 16) ^ ((r & 7) << 4);
                GLOAD_LDS16(kp + (size_t)(m0n + r) * 128 + cb, kt[cur ^ 1] + w * 2048 + rnd * 1024);
                GLOAD_LDS16(vp + (size_t)r * (NV * 2) + m0n * 2 + cb, vt[cur ^ 1] + w * 2048 + rnd * 1024);
            }
        }

        // ---- S^T = K Q : D[key][query], col=lo=query, rows=keys ----
        const char* ktb = kt[cur];
        f32x16 sa[2];
        #pragma unroll
        for (int kb = 0; kb < 2; ++kb) {
            const int krow = kb * 32 + lo;
            const int roff = krow * 128;
            const int swzk = (krow & 7) << 4;
            f32x16 acc{};
            #pragma unroll
            for (int kk = 0; kk < 4; ++kk) {
                const bf16x8 ka = *reinterpret_cast<const bf16x8*>(
                    ktb + roff + ((kk * 32 + hi * 16) ^ swzk));
                acc = __builtin_amdgcn_mfma_f32_32x32x16_bf16(ka, bq[kk], acc, 0, 0, 0);
            }
            sa[kb] = acc;
        }

        // ---- softmax: 31 local fmax + 1 shuffle ----
        float mx = sa[0][0];
        #pragma unroll
        for (int r = 1; r < 16; ++r) mx = fmaxf(mx, sa[0][r]);
        #pragma unroll
        for (int r = 0; r < 16; ++r) mx = fmaxf(mx, sa[1][r]);
        mx = fmaxf(mx, __shfl_xor(mx, 32, 64));

        if (__any(mx > m + 8.0f)) {
            const float mn2 = fmaxf(m, mx);
            const float corr = exp2f(m - mn2);
            m = mn2;
            l *= corr;
            acco[0] *= corr;
            acco[1] *= corr;
        }

        // exp2 + partial sum + pack P -> LDS (keys base = 32kb+8j+4hi)
        float ps = 0.f;
        #pragma unroll
        for (int kb = 0; kb < 2; ++kb) {
            #pragma unroll
            for (int j = 0; j < 4; ++j) {
                float p0 = exp2f(sa[kb][4 * j + 0] - m);
                float p1 = exp2f(sa[kb][4 * j + 1] - m);
                float p2 = exp2f(sa[kb][4 * j + 2] - m);
                float p3 = exp2f(sa[kb][4 * j + 3] - m);
                ps += (p0 + p1) + (p2 + p3);
                uint2 pw;
                pw.x = pack2(p0, p1);
                pw.y = pack2(p2, p3);
                *reinterpret_cast<uint2*>(ptw + ((64 * kb + 16 * j + 8 * hi) ^ swzq)) = pw;
            }
        }
        ps += __shfl_xor(ps, 32, 64);
        l += ps;

        // ---- O^T += V P : D[v][query] ----
        const char* vtb = vt[cur];
        #pragma unroll
        for (int ks = 0; ks < 4; ++ks) {
            union { uint4 u; bf16x8 v; } pf;
            pf.u = *reinterpret_cast<const uint4*>(ptw + ((ks * 32 + hi * 16) ^ swzq));
            #pragma unroll
            for (int vb = 0; vb < 2; ++vb) {
                const int vrow = vb * 32 + lo;
                const bf16x8 va = *reinterpret_cast<const bf16x8*>(
                    vtb + vrow * 128 + ((ks * 32 + hi * 16) ^ ((vrow & 7) << 4)));
                acco[vb] = __builtin_amdgcn_mfma_f32_32x32x16_bf16(va, pf.v, acco[vb], 0, 0, 0);
            }
        }
    }

    // epilogue: lane owns query q; acco[vb][4j+i] = O[q][32vb + 8j + 4hi + i]
    if (q < NV) {
        const size_t obase = ((size_t)(s * 2 + b) * NV + q) * 64;
        #pragma unroll
        for (int vb = 0; vb < 2; ++vb) {
            #pragma unroll
            for (int j = 0; j < 4; ++j) {
                f32x4 o4 = { acco[vb][4 * j + 0], acco[vb][4 * j + 1],
                             acco[vb][4 * j + 2], acco[vb][4 * j + 3] };
                *reinterpret_cast<f32x4*>(&Op[obase + vb * 32 + 8 * j + 4 * hi]) = o4;
            }
        }
        if (hi == 0) {
            float2 t2; t2.x = m; t2.y = l;
            *reinterpret_cast<float2*>(&ml[((size_t)(s * 2 + b) * NV + q) * 2]) = t2;
        }
    }
}

// ---------------------------------------------------------------------------
// Kernel 3: fused split-K combine + output projection (sigma-contiguous).
// (unchanged, R5)
// ---------------------------------------------------------------------------
template<int S>
__global__ __launch_bounds__(256) void projc_kernel(
    const float* __restrict__ Op, const float* __restrict__ ml,
    const float* __restrict__ wo, const float* __restrict__ bo,
    float* __restrict__ out)
{
    __shared__ __align__(16) char bt[64 * 128];
    __shared__ float al[64 * 8];

    const int tid = threadIdx.x;
    const int b   = blockIdx.x / 125;
    const int a   = blockIdx.x % 125;

    if (tid < 64) {
        const int row = a * 64 + tid;
        float M = -1e30f;
        #pragma unroll
        for (int s = 0; s < S; ++s)
            M = fmaxf(M, ml[((size_t)(s * 2 + b) * NV + row) * 2]);
        float L = 0.f, av[S];
        #pragma unroll
        for (int s = 0; s < S; ++s) {
            const float mm = ml[((size_t)(s * 2 + b) * NV + row) * 2];
            const float ll = ml[((size_t)(s * 2 + b) * NV + row) * 2 + 1];
            const float aa = exp2f(mm - M);
            L += ll * aa;
            av[s] = aa;
        }
        const float inv = 1.0f / L;
        #pragma unroll
        for (int s = 0; s < S; ++s) al[tid * 8 + s] = av[s] * inv;
    }
    __syncthreads();

    {
        const int c = tid >> 2, sg = tid & 3;
        f32x4 acc[4] = {{0,0,0,0},{0,0,0,0},{0,0,0,0},{0,0,0,0}};
        #pragma unroll
        for (int s = 0; s < S; ++s) {
            const float fac = al[c * 8 + s];
            const float* base = &Op[((size_t)(s * 2 + b) * NV + a * 64 + c) * 64 + sg * 16];
            #pragma unroll
            for (int qq = 0; qq < 4; ++qq)
                acc[qq] += fac * *reinterpret_cast<const f32x4*>(base + qq * 4);
        }
        #pragma unroll
        for (int qq = 0; qq < 4; ++qq) {
            #pragma unroll
            for (int j = 0; j < 4; ++j) {
                const int v = sg * 16 + qq * 4 + j;
                *reinterpret_cast<bf16_t*>(bt + v * 128 + ((c * 2) ^ ((v & 7) << 4))) =
                    (bf16_t)acc[qq][j];
            }
        }
    }
    __syncthreads();

    const int w  = tid >> 6;
    const int lane = tid & 63;
    const int g  = lane >> 4;
    const int lr = lane & 15;

    const int orow = w * 16 + lr;
    const bf16x8 wa0 = cvt_bf16x8(wo + orow * 64 + 8 * g);
    const bf16x8 wa1 = cvt_bf16x8(wo + orow * 64 + 32 + 8 * g);
    const float4 bo4 = *reinterpret_cast<const float4*>(&bo[w * 16 + 4 * g]);

    const f32x4 zero4 = {0.f, 0.f, 0.f, 0.f};
    #pragma unroll
    for (int nf = 0; nf < 4; ++nf) {
        const int rrow = nf * 16 + lr;
        const bf16x8 gb0 = *reinterpret_cast<const bf16x8*>(
            bt + rrow * 128 + ((16 * g) ^ ((rrow & 7) << 4)));
        const bf16x8 gb1 = *reinterpret_cast<const bf16x8*>(
            bt + rrow * 128 + ((64 + 16 * g) ^ ((rrow & 7) << 4)));
        f32x4 acc = __builtin_amdgcn_mfma_f32_16x16x32_bf16(wa0, gb0, zero4, 0, 0, 0);
        acc = __builtin_amdgcn_mfma_f32_16x16x32_bf16(wa1, gb1, acc, 0, 0, 0);
        #pragma unroll
        for (int j = 0; j < 4; ++j) {
            const int o = w * 16 + 4 * g + j;
            out[((size_t)b * 64 + o) * NV + a * 64 + nf * 16 + lr] = acc[j] + (&bo4.x)[j];
        }
    }
}

// ---------------------------------------------------------------------------
extern "C" void kernel_launch(void* const* d_in, const int* in_sizes, int n_in,
                              void* d_out, int out_size, void* d_ws, size_t ws_size,
                              hipStream_t stream)
{
    const float* x  = (const float*)d_in[0];
    const float* wq = (const float*)d_in[1];
    const float* bq = (const float*)d_in[2];
    const float* wk = (const float*)d_in[3];
    const float* bk = (const float*)d_in[4];
    const float* wv = (const float*)d_in[5];
    const float* bv = (const float*)d_in[6];
    const float* wo = (const float*)d_in[7];
    const float* bo = (const float*)d_in[8];
    float* out = (float*)d_out;

    // ws layout: Q(2,048,000) | K(2,048,000) | Vt(2,048,000) | Op(S*4,096,000) | ml(S*128,000)
    char* ws = (char*)d_ws;
    bf16_t* Q  = (bf16_t*)(ws);
    bf16_t* Kr = (bf16_t*)(ws + 2048000);
    bf16_t* Vt = (bf16_t*)(ws + 4096000);

    int S = 8;
    if (ws_size < 6144000ull + 8ull * 4224000ull) S = 4;
    if (ws_size < 6144000ull + 4ull * 4224000ull) S = 2;
    if (ws_size < 6144000ull + 2ull * 4224000ull) S = 1;

    float* Op = (float*)(ws + 6144000);
    float* ml = (float*)(ws + 6144000 + (size_t)S * 4096000);

    qkv_kernel<<<dim3(2 * 500), dim3(256), 0, stream>>>(x, wq, bq, wk, bk, wv, bv, Q, Kr, Vt);

    if (S == 8) {
        attn_kernel<8><<<dim3(8 * 2 * 63), dim3(256), 0, stream>>>(Q, Kr, Vt, Op, ml);
        projc_kernel<8><<<dim3(2 * 125), dim3(256), 0, stream>>>(Op, ml, wo, bo, out);
    } else if (S == 4) {
        attn_kernel<4><<<dim3(4 * 2 * 63), dim3(256), 0, stream>>>(Q, Kr, Vt, Op, ml);
        projc_kernel<4><<<dim3(2 * 125), dim3(256), 0, stream>>>(Op, ml, wo, bo, out);
    } else if (S == 2) {
        attn_kernel<2><<<dim3(2 * 2 * 63), dim3(256), 0, stream>>>(Q, Kr, Vt, Op, ml);
        projc_kernel<2><<<dim3(2 * 125), dim3(256), 0, stream>>>(Op, ml, wo, bo, out);
    } else {
        attn_kernel<1><<<dim3(1 * 2 * 63), dim3(256), 0, stream>>>(Q, Kr, Vt, Op, ml);
        projc_kernel<1><<<dim3(2 * 125), dim3(256), 0, stream>>>(Op, ml, wo, bo, out);
    }
}